// Round 8
// baseline (307.606 us; speedup 1.0000x reference)
//
#include <hip/hip_runtime.h>
#include <cstdint>
#include <cstddef>

#define F_IN  128
#define F_HID 64
#define F_OUT 40

#define BSH   9     // bucket = dst >> 9 (512 nodes/bucket)
#define NBMAX 256   // supports N <= 131072
#define CHUNK 4096  // edges per partition block

#define BLD_T   512   // build_k threads
#define BLD_CAP 10240 // LDS-staged edges per bucket (40 KB)

typedef __attribute__((ext_vector_type(8))) short short8;   // 8 bf16 = 4 VGPR
typedef __attribute__((ext_vector_type(4))) float f32x4;    // MFMA C/D

// bf16 <-> f32 helpers (RNE on pack; values are finite)
__device__ __forceinline__ unsigned short f2bf(float f) {
  unsigned u = __float_as_uint(f);
  u += 0x7fffu + ((u >> 16) & 1u);
  return (unsigned short)(u >> 16);
}
__device__ __forceinline__ float bf2f(unsigned short b) {
  return __uint_as_float((unsigned)b << 16);
}
__device__ __forceinline__ float bflo(unsigned u) { return __uint_as_float(u << 16); }
__device__ __forceinline__ float bfhi(unsigned u) { return __uint_as_float(u & 0xffff0000u); }
__device__ __forceinline__ unsigned packbf(float lo, float hi) {
  return (unsigned)f2bf(lo) | ((unsigned)f2bf(hi) << 16);
}

// ---------------------------------------------------------------------------
// FRONT (fused): blocks [0,NBLK) run pcount (block 0 additionally emits the
// w2s MFMA-swizzled copy of W2); blocks [NBLK,+gemmBlks) run MFMA GEMM1,
// each converting W1 into a 16 KB LDS B-fragment copy first.
// counts layout: [chunk][256 buckets] — coalesced writes here, coalesced
// column scans in partition_k/build_k (replaces the scanR launch).
// ---------------------------------------------------------------------------
__global__ __launch_bounds__(256) void front_k(const float* __restrict__ x,
                                               const float* __restrict__ W1,
                                               const float* __restrict__ W2,
                                               unsigned short* __restrict__ w2s,
                                               unsigned short* __restrict__ xw, int N,
                                               const int* __restrict__ ei,
                                               int* __restrict__ counts,
                                               int E, int NBLK, int NBUCK) {
  __shared__ int lh[NBMAX];
  __shared__ unsigned short w1l[8192];    // 16 KB swizzled W1 (gemm1 branch)
  int t = threadIdx.x;

  if ((int)blockIdx.x < NBLK) {
    // ---- pcount ----
    int blk = blockIdx.x;
    lh[t] = 0;
    __syncthreads();
    int e0 = blk * CHUNK;
    int n = min(CHUNK, E - e0);
    for (int i = t; i < n; i += 256)
      atomicAdd(&lh[((unsigned)ei[E + e0 + i]) >> BSH], 1);
    __syncthreads();
    counts[blk * 256 + t] = lh[t];      // coalesced; buckets >= NBUCK are 0
    if (blk == 0) {
      // emit swizzled W2 (cols >= 40 zero) for GEMM2
      for (int i = t; i < 3072; i += 256) {
        int f = i >> 9, r = i & 511;
        int lane = r >> 3, jj = r & 7;
        int ct = f >> 1, ks = f & 1;
        int n2 = ct * 16 + (lane & 15);
        int k = ks * 32 + (lane >> 4) * 8 + jj;
        w2s[i] = (n2 < F_OUT) ? f2bf(W2[k * F_OUT + n2]) : (unsigned short)0;
      }
    }
    return;
  }

  // ---- gemm1: convert W1 -> LDS (all threads, coalesced global reads) ----
  {
    int k = t >> 1, n0 = (t & 1) * 32;       // thread owns W1[k][n0..n0+32)
    const float4* wp = (const float4*)(W1 + k * F_HID + n0);
    float4 v[8];
#pragma unroll
    for (int u = 0; u < 8; ++u) v[u] = wp[u];
#pragma unroll
    for (int u = 0; u < 32; ++u) {
      int n = n0 + u;
      float f = ((const float*)v)[u];
      int idx = ((n >> 4) * 4 + (k >> 5)) * 512 +
                (((k >> 3) & 3) * 16 + (n & 15)) * 8 + (k & 7);
      w1l[idx] = f2bf(f);
    }
  }
  __syncthreads();

  int gblk = blockIdx.x - NBLK;
  int lane = t & 63;
  int wid  = gblk * 4 + (t >> 6);
  int row0 = wid * 16;
  if (row0 >= N) return;
  int m = lane & 15, q = lane >> 4;

  if (row0 + 16 <= N) {
    short8 b[16];
#pragma unroll
    for (int f = 0; f < 16; ++f)
      b[f] = *(const short8*)(w1l + f * 512 + lane * 8);

    short8 a[4];
#pragma unroll
    for (int ks = 0; ks < 4; ++ks) {
      const float* xp = x + (size_t)(row0 + m) * F_IN + ks * 32 + q * 8;
      float4 v0 = *(const float4*)xp;
      float4 v1 = *(const float4*)(xp + 4);
      short8 tt;
      tt[0] = (short)f2bf(v0.x); tt[1] = (short)f2bf(v0.y);
      tt[2] = (short)f2bf(v0.z); tt[3] = (short)f2bf(v0.w);
      tt[4] = (short)f2bf(v1.x); tt[5] = (short)f2bf(v1.y);
      tt[6] = (short)f2bf(v1.z); tt[7] = (short)f2bf(v1.w);
      a[ks] = tt;
    }

    f32x4 z = {0.f, 0.f, 0.f, 0.f};
    f32x4 acc[4] = {z, z, z, z};
#pragma unroll
    for (int ct = 0; ct < 4; ++ct)
#pragma unroll
      for (int ks = 0; ks < 4; ++ks)
        acc[ct] = __builtin_amdgcn_mfma_f32_16x16x32_bf16(a[ks], b[ct * 4 + ks],
                                                          acc[ct], 0, 0, 0);
#pragma unroll
    for (int ct = 0; ct < 4; ++ct)
#pragma unroll
      for (int r = 0; r < 4; ++r) {
        int row = row0 + q * 4 + r;                 // D: col=lane&15, row=q*4+reg
        xw[(size_t)row * F_HID + ct * 16 + m] = f2bf(acc[ct][r]);
      }
  } else {
    for (int r = 0; r < 16 && row0 + r < N; ++r) { // tail: col = lane
      const float* xr = x + (size_t)(row0 + r) * F_IN;
      float s = 0.f;
      for (int k = 0; k < F_IN; ++k) s = fmaf(xr[k], W1[k * F_HID + lane], s);
      xw[(size_t)(row0 + r) * F_HID + lane] = f2bf(s);
    }
  }
}

// ---------------------------------------------------------------------------
// Multisplit P2: stable partition into bucket-major packed ebuf.
// Thread t (bucket t) makes ONE coalesced pass over its counts column,
// producing prefix-over-chunks(<blk) and the column total — no scanR kernel.
// ebuf entries: (dst & 511) << 17 | src  (src < 131072).
// ---------------------------------------------------------------------------
__global__ __launch_bounds__(256) void partition_k(const int* __restrict__ counts,
                                                   const int* __restrict__ ei,
                                                   unsigned* __restrict__ ebuf,
                                                   int E, int NBLK, int NBUCK) {
  __shared__ uint2 slots[CHUNK];          // 32 KB
  __shared__ int scn[NBMAX], lcur[NBMAX], gadj[NBMAX];
  int t = threadIdx.x, blk = blockIdx.x;
  int e0 = blk * CHUNK;
  int n = min(CHUNK, E - e0);

  // one coalesced pass over column t: prefix before this chunk + total
  int pre = 0, tot = 0;
  for (int j = 0; j < NBLK; ++j) {
    int c = counts[j * 256 + t];
    pre += (j < blk) ? c : 0;
    tot += c;
  }
  // bucketBase(t) = exclusive scan of totals
  scn[t] = tot;
  __syncthreads();
  for (int off = 1; off < 256; off <<= 1) {
    int add = (t >= off) ? scn[t - off] : 0;
    __syncthreads();
    scn[t] += add;
    __syncthreads();
  }
  int base0 = (scn[t] - tot) + pre;       // global base of this chunk's run
  int cnt = counts[blk * 256 + t];
  __syncthreads();

  // rank within chunk (stable): exclusive scan of per-bucket chunk counts
  scn[t] = cnt;
  __syncthreads();
  for (int off = 1; off < 256; off <<= 1) {
    int add = (t >= off) ? scn[t - off] : 0;
    __syncthreads();
    scn[t] += add;
    __syncthreads();
  }
  int excl = scn[t] - cnt;
  lcur[t] = excl;
  gadj[t] = base0 - excl;
  __syncthreads();

  for (int i = t; i < n; i += 256) {
    int s = ei[e0 + i], d = ei[E + e0 + i];
    int pos = atomicAdd(&lcur[((unsigned)d) >> BSH], 1);
    slots[pos] = make_uint2((unsigned)s, (unsigned)d);
  }
  __syncthreads();
  for (int i = t; i < n; i += 256) {
    uint2 sd = slots[i];
    unsigned pk = ((sd.y & 511u) << 17) | sd.x;
    ebuf[gadj[sd.y >> BSH] + i] = pk;
  }
}

// ---------------------------------------------------------------------------
// Bucket-local CSR build: bucket bases from coalesced column-total scan;
// LDS-stage the bucket's packed edges; histogram + scan -> row_ptr; cursor
// fill. csr = plain src.
// ---------------------------------------------------------------------------
__global__ __launch_bounds__(BLD_T) void build_k(const unsigned* __restrict__ ebuf,
                                                 const int* __restrict__ counts,
                                                 int* __restrict__ row_ptr,
                                                 int* __restrict__ csr,
                                                 int N, int E, int NBLK, int NBUCK) {
  __shared__ int hist[512];
  __shared__ int psc[256];
  __shared__ int btot[NBMAX];
  __shared__ unsigned stg[BLD_CAP];       // 40 KB
  int t = threadIdx.x, b = blockIdx.x;
  int nodeBase = b << BSH;

  // column totals (threads 0..255), then inclusive scan -> S, T
  if (t < 256) {
    int tot = 0;
    for (int j = 0; j < NBLK; ++j) tot += counts[j * 256 + t];
    btot[t] = tot;
  }
  __syncthreads();
  for (int off = 1; off < 256; off <<= 1) {
    int add = (t >= off && t < 256) ? btot[t - off] : 0;
    __syncthreads();
    if (t < 256) btot[t] += add;
    __syncthreads();
  }
  int S = (b > 0) ? btot[b - 1] : 0;
  int T = btot[b];
  int n = T - S;
  bool useLds = (n <= BLD_CAP);
  __syncthreads();

  if (t < 512) hist[t] = 0;
  __syncthreads();
  for (int i = t; i < n; i += BLD_T) {
    unsigned v = ebuf[S + i];
    if (useLds) stg[i] = v;
    atomicAdd(&hist[v >> 17], 1);
  }
  __syncthreads();

  int v0 = 0, v1 = 0, pair = 0;
  if (t < 256) {
    v0 = hist[2 * t]; v1 = hist[2 * t + 1];
    pair = v0 + v1;
    psc[t] = pair;
  }
  __syncthreads();
  for (int off = 1; off < 256; off <<= 1) {
    int add = (t >= off && t < 256) ? psc[t - off] : 0;
    __syncthreads();
    if (t < 256) psc[t] += add;
    __syncthreads();
  }
  if (t < 256) {
    int ep = psc[t] - pair;
    int e0 = ep, e1 = ep + v0;
    int node0 = nodeBase + 2 * t;
    if (node0 < N) row_ptr[node0] = S + e0;
    if (node0 + 1 < N) row_ptr[node0 + 1] = S + e1;
    hist[2 * t] = e0; hist[2 * t + 1] = e1;   // reuse as cursors
  }
  if (b == 0 && t == 0) row_ptr[N] = E;
  __syncthreads();
  for (int i = t; i < n; i += BLD_T) {
    unsigned v = useLds ? stg[i] : ebuf[S + i];
    int pos = atomicAdd(&hist[v >> 17], 1);
    csr[S + pos] = (int)(v & 0x1FFFFu);
  }
}

// ---------------------------------------------------------------------------
// 8-wide gather macro bodies (latency-bound gathers -> 8 outstanding
// dwordx4 loads per lane before the accumulate chain waits).
// ---------------------------------------------------------------------------
#define GATHER8(SRC, STRIDE_SH)                                              \
  for (; i + 7 < end; i += 8) {                                              \
    int s0 = csr[i],     s1 = csr[i + 1], s2 = csr[i + 2], s3 = csr[i + 3];  \
    int s4 = csr[i + 4], s5 = csr[i + 5], s6 = csr[i + 6], s7 = csr[i + 7];  \
    uint4 v0 = *(const uint4*)(SRC + ((size_t)s0 << STRIDE_SH) + (part << 3)); \
    uint4 v1 = *(const uint4*)(SRC + ((size_t)s1 << STRIDE_SH) + (part << 3)); \
    uint4 v2 = *(const uint4*)(SRC + ((size_t)s2 << STRIDE_SH) + (part << 3)); \
    uint4 v3 = *(const uint4*)(SRC + ((size_t)s3 << STRIDE_SH) + (part << 3)); \
    uint4 v4 = *(const uint4*)(SRC + ((size_t)s4 << STRIDE_SH) + (part << 3)); \
    uint4 v5 = *(const uint4*)(SRC + ((size_t)s5 << STRIDE_SH) + (part << 3)); \
    uint4 v6 = *(const uint4*)(SRC + ((size_t)s6 << STRIDE_SH) + (part << 3)); \
    uint4 v7 = *(const uint4*)(SRC + ((size_t)s7 << STRIDE_SH) + (part << 3)); \
    ACC8(acc, v0); ACC8(bcc, v1); ACC8(acc, v2); ACC8(bcc, v3);              \
    ACC8(acc, v4); ACC8(bcc, v5); ACC8(acc, v6); ACC8(bcc, v7);              \
  }                                                                          \
  for (; i < end; ++i) {                                                     \
    int s = csr[i];                                                          \
    uint4 v = *(const uint4*)(SRC + ((size_t)s << STRIDE_SH) + (part << 3)); \
    ACC8(acc, v);                                                            \
  }

#define ACC8(A, V)                                                           \
  A[0] += bflo(V.x); A[1] += bfhi(V.x); A[2] += bflo(V.y); A[3] += bfhi(V.y);\
  A[4] += bflo(V.z); A[5] += bfhi(V.z); A[6] += bflo(V.w); A[7] += bfhi(V.w);

// ---------------------------------------------------------------------------
// FUSED aggregation-1 + bias1 + ReLU + GEMM2 (row-parallel, lane-private).
// Wave = 8 rows (lane: row=lane>>3, part=lane&7 owning 8 cols = 16 B).
// 8-wide unrolled gather. h[32][64] staged in XOR-swizzled LDS; waves 0/1
// run the 64x40 MFMA GEMM -> hw[N][64] bf16 (cols 0..39, 128-B rows).
// ---------------------------------------------------------------------------
__global__ __launch_bounds__(256) void agg1g2_k(const unsigned short* __restrict__ xw,
                                                const int* __restrict__ row_ptr,
                                                const int* __restrict__ csr,
                                                const float* __restrict__ b1,
                                                const unsigned short* __restrict__ w2s,
                                                const float* __restrict__ W2,
                                                unsigned short* __restrict__ hw, int N) {
  __shared__ uint4 hsm[32][8];            // 4 KB, XOR-swizzled on part
  int t = threadIdx.x;
  int wave = t >> 6, lane = t & 63;
  int blockRow0 = blockIdx.x * 32;
  int row = blockRow0 + wave * 8 + (lane >> 3);
  int part = lane & 7;
  bool live = row < N;

  int start = live ? row_ptr[row] : 0;
  int end   = live ? row_ptr[row + 1] : 0;

  float acc[8], bcc[8];
#pragma unroll
  for (int j = 0; j < 8; ++j) { acc[j] = 0.f; bcc[j] = 0.f; }

  int i = start;
  GATHER8(xw, 6)

  if (live) {
    int c0 = part << 3;
    float4 bA = *(const float4*)(b1 + c0);
    float4 bB = *(const float4*)(b1 + c0 + 4);
    float r0 = fmaxf(acc[0] + bcc[0] + bA.x, 0.f);
    float r1 = fmaxf(acc[1] + bcc[1] + bA.y, 0.f);
    float r2 = fmaxf(acc[2] + bcc[2] + bA.z, 0.f);
    float r3 = fmaxf(acc[3] + bcc[3] + bA.w, 0.f);
    float r4 = fmaxf(acc[4] + bcc[4] + bB.x, 0.f);
    float r5 = fmaxf(acc[5] + bcc[5] + bB.y, 0.f);
    float r6 = fmaxf(acc[6] + bcc[6] + bB.z, 0.f);
    float r7 = fmaxf(acc[7] + bcc[7] + bB.w, 0.f);
    uint4 o = make_uint4(packbf(r0, r1), packbf(r2, r3),
                         packbf(r4, r5), packbf(r6, r7));
    int lr = row - blockRow0;
    hsm[lr][part ^ (lr & 7)] = o;
  }
  __syncthreads();

  // ---- GEMM2: h[32][64] @ W2[64][40] -> hw (stride 64, cols 0..39) ----
  if (wave < 2) {
    int frow0 = blockRow0 + wave * 16;
    if (frow0 >= N) return;
    int m = lane & 15, q = lane >> 4;
    if (frow0 + 16 <= N) {
      short8 b[6];
#pragma unroll
      for (int f = 0; f < 6; ++f)
        b[f] = *(const short8*)(w2s + f * 512 + lane * 8);
      short8 a[2];
#pragma unroll
      for (int ks = 0; ks < 2; ++ks) {
        int lr = wave * 16 + m;
        int pp = ks * 4 + q;
        a[ks] = *(const short8*)&hsm[lr][pp ^ (lr & 7)];
      }
      f32x4 z = {0.f, 0.f, 0.f, 0.f};
      f32x4 acc2[3] = {z, z, z};
#pragma unroll
      for (int ct = 0; ct < 3; ++ct)
#pragma unroll
        for (int ks = 0; ks < 2; ++ks)
          acc2[ct] = __builtin_amdgcn_mfma_f32_16x16x32_bf16(
              a[ks], b[ct * 2 + ks], acc2[ct], 0, 0, 0);
#pragma unroll
      for (int ct = 0; ct < 3; ++ct)
#pragma unroll
        for (int r = 0; r < 4; ++r) {
          int row2 = frow0 + q * 4 + r;
          int c = ct * 16 + m;
          if (c < F_OUT) hw[(size_t)row2 * F_HID + c] = f2bf(acc2[ct][r]);
        }
    } else {
      for (int r = 0; r < 16; ++r) {            // tail rows (N%16 != 0)
        int row2 = frow0 + r;
        if (row2 >= N) break;
        if (lane < F_OUT) {
          int lr = wave * 16 + r;
          float s = 0.f;
          for (int k = 0; k < F_HID; ++k) {
            const unsigned short* hp =
                (const unsigned short*)&hsm[lr][(k >> 3) ^ (lr & 7)];
            s = fmaf(bf2f(hp[k & 7]), W2[k * F_OUT + lane], s);
          }
          hw[(size_t)row2 * F_HID + lane] = f2bf(s);
        }
      }
    }
  }
}

// ---------------------------------------------------------------------------
// Aggregation layer 2 + bias2 + log_softmax — 12 rows x 5 parts per wave,
// 8-wide unrolled gather. Softmax reduces across the 5-lane group via shfl.
// ---------------------------------------------------------------------------
__global__ __launch_bounds__(256) void agg2_ls_k(const unsigned short* __restrict__ hw,
                                                 const int* __restrict__ row_ptr,
                                                 const int* __restrict__ csr,
                                                 const float* __restrict__ b2,
                                                 float* __restrict__ out, int N) {
  int t = threadIdx.x;
  int wave = t >> 6, lane = t & 63;
  int grp = lane / 5;                      // 12 groups; lanes 60..63 idle
  int part = lane - grp * 5;
  int row = blockIdx.x * 48 + wave * 12 + grp;
  bool live = (grp < 12) && (row < N);

  int start = live ? row_ptr[row] : 0;
  int end   = live ? row_ptr[row + 1] : 0;

  float acc[8], bcc[8];
#pragma unroll
  for (int j = 0; j < 8; ++j) { acc[j] = 0.f; bcc[j] = 0.f; }

  int i = start;
  GATHER8(hw, 6)

  float vj[8];
  float mx = -3.4e38f;
  if (live) {
    int c0 = part << 3;
    float4 bA = *(const float4*)(b2 + c0);
    float4 bB = *(const float4*)(b2 + c0 + 4);
    vj[0] = acc[0] + bcc[0] + bA.x; vj[1] = acc[1] + bcc[1] + bA.y;
    vj[2] = acc[2] + bcc[2] + bA.z; vj[3] = acc[3] + bcc[3] + bA.w;
    vj[4] = acc[4] + bcc[4] + bB.x; vj[5] = acc[5] + bcc[5] + bB.y;
    vj[6] = acc[6] + bcc[6] + bB.z; vj[7] = acc[7] + bcc[7] + bB.w;
#pragma unroll
    for (int q = 0; q < 8; ++q) mx = fmaxf(mx, vj[q]);
  }
  int g0 = (grp < 12 ? grp : 0) * 5;
  float mxAll = mx;
#pragma unroll
  for (int q = 0; q < 5; ++q) mxAll = fmaxf(mxAll, __shfl(mx, g0 + q, 64));
  float ex = 0.f;
  if (live) {
#pragma unroll
    for (int q = 0; q < 8; ++q) ex += __expf(vj[q] - mxAll);
  }
  float exAll = 0.f;
#pragma unroll
  for (int q = 0; q < 5; ++q) exAll += __shfl(ex, g0 + q, 64);
  float lse = __logf(exAll) + mxAll;

  if (live) {
    int c0 = part << 3;
    float* op = out + (size_t)row * F_OUT + c0;
    *(float4*)op = make_float4(vj[0] - lse, vj[1] - lse, vj[2] - lse, vj[3] - lse);
    *(float4*)(op + 4) = make_float4(vj[4] - lse, vj[5] - lse, vj[6] - lse, vj[7] - lse);
  }
}

// ---------------------------------------------------------------------------
// ws layout (≈33 MB):
//   regA : xw[N,64] bf16
//   regB : ebuf[E] u32 — reused as hw[N,64] bf16 (ebuf dead after build)
//   row_ptr : N+1 | csr : E | counts : NBLK*256 | w2s : 3072
// ---------------------------------------------------------------------------
extern "C" void kernel_launch(void* const* d_in, const int* in_sizes, int n_in,
                              void* d_out, int out_size, void* d_ws, size_t ws_size,
                              hipStream_t stream) {
  const float* x  = (const float*)d_in[0];
  const int*   ei = (const int*)d_in[1];
  const float* W1 = (const float*)d_in[2];
  const float* b1 = (const float*)d_in[3];
  const float* W2 = (const float*)d_in[4];
  const float* b2 = (const float*)d_in[5];

  int N = in_sizes[0] / F_IN;
  int E = in_sizes[1] / 2;

  char* base = (char*)d_ws;
  size_t szA = (size_t)N * F_HID * sizeof(unsigned short);
  size_t szEb = (size_t)E * sizeof(unsigned);
  size_t szHw = (size_t)N * F_HID * sizeof(unsigned short);
  size_t szB = (szEb > szHw) ? szEb : szHw;
  unsigned short* xw = (unsigned short*)base;
  char* regB = base + ((szA + 255) & ~(size_t)255);
  unsigned* ebuf       = (unsigned*)regB;
  unsigned short* hw   = (unsigned short*)regB;
  int* row_ptr = (int*)(regB + ((szB + 255) & ~(size_t)255));
  int* csr     = row_ptr + N + 1;
  int* counts  = csr + E;
  float* out = (float*)d_out;

  int NBLK  = (E + CHUNK - 1) / CHUNK;
  int NBUCK = (N + 511) >> BSH;
  unsigned short* w2s =
      (unsigned short*)(((uintptr_t)(counts + NBLK * 256) + 63) & ~(uintptr_t)63);
  int gemmGrid = (N + 63) / 64;
  int aggGrid1 = (N + 31) / 32;      // agg1g2: 32 rows per block
  int aggGrid2 = (N + 47) / 48;      // agg2: 48 rows per block (12/wave)

  // fused: pcount + w2s (blocks 0..NBLK-1) + gemm1 (remaining blocks)
  front_k<<<NBLK + gemmGrid, 256, 0, stream>>>(x, W1, W2, w2s, xw, N,
                                               ei, counts, E, NBLK, NBUCK);

  partition_k<<<NBLK, 256, 0, stream>>>(counts, ei, ebuf, E, NBLK, NBUCK);
  build_k<<<NBUCK, BLD_T, 0, stream>>>(ebuf, counts, row_ptr, csr,
                                       N, E, NBLK, NBUCK);

  agg1g2_k<<<aggGrid1, 256, 0, stream>>>(xw, row_ptr, csr, b1, w2s, W2, hw, N);
  agg2_ls_k<<<aggGrid2, 256, 0, stream>>>(hw, row_ptr, csr, b2, out, N);
}

// Round 9
// 215.178 us; speedup vs baseline: 1.4295x; 1.4295x over previous
//
#include <hip/hip_runtime.h>
#include <cstdint>
#include <cstddef>

#define F_IN  128
#define F_HID 64
#define F_OUT 40

#define BSH   9     // bucket = dst >> 9 (512 nodes/bucket)
#define NBMAX 256   // supports N <= 131072
#define CHUNK 4096  // edges per partition block

#define BLD_T 1024  // build_k threads (16 waves/CU for latency/atomic phases)

typedef __attribute__((ext_vector_type(8))) short short8;   // 8 bf16 = 4 VGPR
typedef __attribute__((ext_vector_type(4))) float f32x4;    // MFMA C/D

// bf16 <-> f32 helpers (RNE on pack; values are finite)
__device__ __forceinline__ unsigned short f2bf(float f) {
  unsigned u = __float_as_uint(f);
  u += 0x7fffu + ((u >> 16) & 1u);
  return (unsigned short)(u >> 16);
}
__device__ __forceinline__ float bf2f(unsigned short b) {
  return __uint_as_float((unsigned)b << 16);
}
__device__ __forceinline__ float bflo(unsigned u) { return __uint_as_float(u << 16); }
__device__ __forceinline__ float bfhi(unsigned u) { return __uint_as_float(u & 0xffff0000u); }
__device__ __forceinline__ unsigned packbf(float lo, float hi) {
  return (unsigned)f2bf(lo) | ((unsigned)f2bf(hi) << 16);
}

// ---------------------------------------------------------------------------
// FRONT (fused): blocks [0,NBLK) run pcount (block 0 additionally emits the
// w2s MFMA-swizzled copy of W2); blocks [NBLK,+gemmBlks) run MFMA GEMM1,
// each converting W1 into a 16 KB LDS B-fragment copy first.
// counts layout: [NBUCK][NB1] with NB1 = NBLK+1 (col NBLK = row totals,
// filled by scanR_k).
// ---------------------------------------------------------------------------
__global__ __launch_bounds__(256) void front_k(const float* __restrict__ x,
                                               const float* __restrict__ W1,
                                               const float* __restrict__ W2,
                                               unsigned short* __restrict__ w2s,
                                               unsigned short* __restrict__ xw, int N,
                                               const int* __restrict__ ei,
                                               int* __restrict__ counts,
                                               int E, int NBLK, int NB1, int NBUCK) {
  __shared__ int lh[NBMAX];
  __shared__ unsigned short w1l[8192];    // 16 KB swizzled W1 (gemm1 branch)
  int t = threadIdx.x;

  if ((int)blockIdx.x < NBLK) {
    // ---- pcount ----
    int blk = blockIdx.x;
    lh[t] = 0;
    __syncthreads();
    int e0 = blk * CHUNK;
    int n = min(CHUNK, E - e0);
    for (int i = t; i < n; i += 256)
      atomicAdd(&lh[((unsigned)ei[E + e0 + i]) >> BSH], 1);
    __syncthreads();
    if (t < NBUCK) counts[t * NB1 + blk] = lh[t];
    if (blk == 0) {
      // emit swizzled W2 (cols >= 40 zero) for GEMM2
      for (int i = t; i < 3072; i += 256) {
        int f = i >> 9, r = i & 511;
        int lane = r >> 3, jj = r & 7;
        int ct = f >> 1, ks = f & 1;
        int n2 = ct * 16 + (lane & 15);
        int k = ks * 32 + (lane >> 4) * 8 + jj;
        w2s[i] = (n2 < F_OUT) ? f2bf(W2[k * F_OUT + n2]) : (unsigned short)0;
      }
    }
    return;
  }

  // ---- gemm1: convert W1 -> LDS (all threads, coalesced global reads) ----
  {
    int k = t >> 1, n0 = (t & 1) * 32;       // thread owns W1[k][n0..n0+32)
    const float4* wp = (const float4*)(W1 + k * F_HID + n0);
    float4 v[8];
#pragma unroll
    for (int u = 0; u < 8; ++u) v[u] = wp[u];
#pragma unroll
    for (int u = 0; u < 32; ++u) {
      int n = n0 + u;
      float f = ((const float*)v)[u];
      int idx = ((n >> 4) * 4 + (k >> 5)) * 512 +
                (((k >> 3) & 3) * 16 + (n & 15)) * 8 + (k & 7);
      w1l[idx] = f2bf(f);
    }
  }
  __syncthreads();

  int gblk = blockIdx.x - NBLK;
  int lane = t & 63;
  int wid  = gblk * 4 + (t >> 6);
  int row0 = wid * 16;
  if (row0 >= N) return;
  int m = lane & 15, q = lane >> 4;

  if (row0 + 16 <= N) {
    short8 b[16];
#pragma unroll
    for (int f = 0; f < 16; ++f)
      b[f] = *(const short8*)(w1l + f * 512 + lane * 8);

    short8 a[4];
#pragma unroll
    for (int ks = 0; ks < 4; ++ks) {
      const float* xp = x + (size_t)(row0 + m) * F_IN + ks * 32 + q * 8;
      float4 v0 = *(const float4*)xp;
      float4 v1 = *(const float4*)(xp + 4);
      short8 tt;
      tt[0] = (short)f2bf(v0.x); tt[1] = (short)f2bf(v0.y);
      tt[2] = (short)f2bf(v0.z); tt[3] = (short)f2bf(v0.w);
      tt[4] = (short)f2bf(v1.x); tt[5] = (short)f2bf(v1.y);
      tt[6] = (short)f2bf(v1.z); tt[7] = (short)f2bf(v1.w);
      a[ks] = tt;
    }

    f32x4 z = {0.f, 0.f, 0.f, 0.f};
    f32x4 acc[4] = {z, z, z, z};
#pragma unroll
    for (int ct = 0; ct < 4; ++ct)
#pragma unroll
      for (int ks = 0; ks < 4; ++ks)
        acc[ct] = __builtin_amdgcn_mfma_f32_16x16x32_bf16(a[ks], b[ct * 4 + ks],
                                                          acc[ct], 0, 0, 0);
#pragma unroll
    for (int ct = 0; ct < 4; ++ct)
#pragma unroll
      for (int r = 0; r < 4; ++r) {
        int row = row0 + q * 4 + r;                 // D: col=lane&15, row=q*4+reg
        xw[(size_t)row * F_HID + ct * 16 + m] = f2bf(acc[ct][r]);
      }
  } else {
    for (int r = 0; r < 16 && row0 + r < N; ++r) { // tail: col = lane
      const float* xr = x + (size_t)(row0 + r) * F_IN;
      float s = 0.f;
      for (int k = 0; k < F_IN; ++k) s = fmaf(xr[k], W1[k * F_HID + lane], s);
      xw[(size_t)(row0 + r) * F_HID + lane] = f2bf(s);
    }
  }
}

// ---------------------------------------------------------------------------
// Row-wise exclusive scan: block b scans counts[b][0..NBLK) in place and
// writes the row total to counts[b][NBLK]. 196 parallel blocks.
// ---------------------------------------------------------------------------
__global__ __launch_bounds__(256) void scanR_k(int* __restrict__ counts,
                                               int NBLK, int NB1) {
  __shared__ int sm[512];
  __shared__ int psc[256];
  int t = threadIdx.x;
  int* c = counts + blockIdx.x * NB1;

  sm[t]       = (t < NBLK)       ? c[t]       : 0;
  sm[t + 256] = (t + 256 < NBLK) ? c[t + 256] : 0;
  __syncthreads();

  int v0 = sm[2 * t], v1 = sm[2 * t + 1];
  int pair = v0 + v1;
  psc[t] = pair;
  __syncthreads();
  for (int off = 1; off < 256; off <<= 1) {
    int add = (t >= off) ? psc[t - off] : 0;
    __syncthreads();
    psc[t] += add;
    __syncthreads();
  }
  int ep = psc[t] - pair;            // exclusive pair base
  if (2 * t < NBLK)     c[2 * t]     = ep;
  if (2 * t + 1 < NBLK) c[2 * t + 1] = ep + v0;
  if (t == 0) c[NBLK] = psc[255];    // row total
}

// ---------------------------------------------------------------------------
// Multisplit P2: stable partition into bucket-major packed ebuf.
// Bucket bases recomputed redundantly: LDS scan of the row totals.
// ebuf entries: (dst & 511) << 17 | src  (src < 131072).
// ---------------------------------------------------------------------------
__global__ __launch_bounds__(256) void partition_k(const int* __restrict__ counts,
                                                   const int* __restrict__ ei,
                                                   unsigned* __restrict__ ebuf,
                                                   int E, int NBLK, int NB1,
                                                   int NBUCK) {
  __shared__ uint2 slots[CHUNK];          // 32 KB
  __shared__ int scn[NBMAX], lcur[NBMAX], gadj[NBMAX];
  int t = threadIdx.x, blk = blockIdx.x;
  int e0 = blk * CHUNK;
  int n = min(CHUNK, E - e0);

  // bucket base: exclusive scan of row totals
  int rowTot = (t < NBUCK) ? counts[t * NB1 + NBLK] : 0;
  scn[t] = rowTot;
  __syncthreads();
  for (int off = 1; off < 256; off <<= 1) {
    int add = (t >= off) ? scn[t - off] : 0;
    __syncthreads();
    scn[t] += add;
    __syncthreads();
  }
  int bucketBase = scn[t] - rowTot;       // exclusive
  __syncthreads();

  // per-bucket count & global base for this chunk
  int cnt = 0, base0 = 0;
  if (t < NBUCK) {
    int cpre  = counts[t * NB1 + blk];
    int cnext = counts[t * NB1 + blk + 1];
    cnt = cnext - cpre;
    base0 = bucketBase + cpre;
  }
  scn[t] = cnt;
  __syncthreads();
  for (int off = 1; off < 256; off <<= 1) {
    int add = (t >= off) ? scn[t - off] : 0;
    __syncthreads();
    scn[t] += add;
    __syncthreads();
  }
  int excl = scn[t] - cnt;
  if (t < NBUCK) { lcur[t] = excl; gadj[t] = base0 - excl; }
  __syncthreads();

  for (int i = t; i < n; i += 256) {
    int s = ei[e0 + i], d = ei[E + e0 + i];
    int pos = atomicAdd(&lcur[((unsigned)d) >> BSH], 1);
    slots[pos] = make_uint2((unsigned)s, (unsigned)d);
  }
  __syncthreads();
  for (int i = t; i < n; i += 256) {
    uint2 sd = slots[i];
    unsigned pk = ((sd.y & 511u) << 17) | sd.x;
    ebuf[gadj[sd.y >> BSH] + i] = pk;
  }
}

// ---------------------------------------------------------------------------
// Bucket-local CSR build: 1024 threads (16 waves/CU — the histogram and
// cursor phases are latency/atomic-bound, R7 showed 8 waves starves them).
// No LDS edge staging: the bucket's ebuf slice is contiguous and L2-hot,
// re-reading it is cheaper than 40 KB of LDS (4 KB total LDS now).
// ---------------------------------------------------------------------------
__global__ __launch_bounds__(BLD_T) void build_k(const unsigned* __restrict__ ebuf,
                                                 const int* __restrict__ counts,
                                                 int* __restrict__ row_ptr,
                                                 int* __restrict__ csr,
                                                 int N, int E, int NBLK, int NB1,
                                                 int NBUCK) {
  __shared__ int hist[512];
  __shared__ int psc[256];
  __shared__ int btot[NBMAX];
  int t = threadIdx.x, b = blockIdx.x;
  int nodeBase = b << BSH;

  // inclusive scan of row totals -> S, T for this bucket
  if (t < 256) btot[t] = (t < NBUCK) ? counts[t * NB1 + NBLK] : 0;
  __syncthreads();
  for (int off = 1; off < 256; off <<= 1) {
    int add = (t >= off && t < 256) ? btot[t - off] : 0;
    __syncthreads();
    if (t < 256) btot[t] += add;
    __syncthreads();
  }
  int S = (b > 0) ? btot[b - 1] : 0;
  int T = btot[b];
  int n = T - S;
  __syncthreads();

  if (t < 512) hist[t] = 0;
  __syncthreads();
  for (int i = t; i < n; i += BLD_T)
    atomicAdd(&hist[ebuf[S + i] >> 17], 1);
  __syncthreads();

  int v0 = 0, v1 = 0, pair = 0;
  if (t < 256) {
    v0 = hist[2 * t]; v1 = hist[2 * t + 1];
    pair = v0 + v1;
    psc[t] = pair;
  }
  __syncthreads();
  for (int off = 1; off < 256; off <<= 1) {
    int add = (t >= off && t < 256) ? psc[t - off] : 0;
    __syncthreads();
    if (t < 256) psc[t] += add;
    __syncthreads();
  }
  if (t < 256) {
    int ep = psc[t] - pair;
    int e0 = ep, e1 = ep + v0;
    int node0 = nodeBase + 2 * t;
    if (node0 < N) row_ptr[node0] = S + e0;
    if (node0 + 1 < N) row_ptr[node0 + 1] = S + e1;
    hist[2 * t] = e0; hist[2 * t + 1] = e1;   // reuse as cursors
  }
  if (b == 0 && t == 0) row_ptr[N] = E;
  __syncthreads();
  for (int i = t; i < n; i += BLD_T) {
    unsigned v = ebuf[S + i];
    int pos = atomicAdd(&hist[v >> 17], 1);
    csr[S + pos] = (int)(v & 0x1FFFFu);
  }
}

// ---------------------------------------------------------------------------
// 8-wide gather macro bodies (latency-bound gathers -> 8 outstanding
// dwordx4 loads per lane before the accumulate chain waits).
// ---------------------------------------------------------------------------
#define GATHER8(SRC, STRIDE_SH)                                              \
  for (; i + 7 < end; i += 8) {                                              \
    int s0 = csr[i],     s1 = csr[i + 1], s2 = csr[i + 2], s3 = csr[i + 3];  \
    int s4 = csr[i + 4], s5 = csr[i + 5], s6 = csr[i + 6], s7 = csr[i + 7];  \
    uint4 v0 = *(const uint4*)(SRC + ((size_t)s0 << STRIDE_SH) + (part << 3)); \
    uint4 v1 = *(const uint4*)(SRC + ((size_t)s1 << STRIDE_SH) + (part << 3)); \
    uint4 v2 = *(const uint4*)(SRC + ((size_t)s2 << STRIDE_SH) + (part << 3)); \
    uint4 v3 = *(const uint4*)(SRC + ((size_t)s3 << STRIDE_SH) + (part << 3)); \
    uint4 v4 = *(const uint4*)(SRC + ((size_t)s4 << STRIDE_SH) + (part << 3)); \
    uint4 v5 = *(const uint4*)(SRC + ((size_t)s5 << STRIDE_SH) + (part << 3)); \
    uint4 v6 = *(const uint4*)(SRC + ((size_t)s6 << STRIDE_SH) + (part << 3)); \
    uint4 v7 = *(const uint4*)(SRC + ((size_t)s7 << STRIDE_SH) + (part << 3)); \
    ACC8(acc, v0); ACC8(bcc, v1); ACC8(acc, v2); ACC8(bcc, v3);              \
    ACC8(acc, v4); ACC8(bcc, v5); ACC8(acc, v6); ACC8(bcc, v7);              \
  }                                                                          \
  for (; i < end; ++i) {                                                     \
    int s = csr[i];                                                          \
    uint4 v = *(const uint4*)(SRC + ((size_t)s << STRIDE_SH) + (part << 3)); \
    ACC8(acc, v);                                                            \
  }

#define ACC8(A, V)                                                           \
  A[0] += bflo(V.x); A[1] += bfhi(V.x); A[2] += bflo(V.y); A[3] += bfhi(V.y);\
  A[4] += bflo(V.z); A[5] += bfhi(V.z); A[6] += bflo(V.w); A[7] += bfhi(V.w);

// ---------------------------------------------------------------------------
// FUSED aggregation-1 + bias1 + ReLU + GEMM2 (row-parallel, lane-private).
// Wave = 8 rows (lane: row=lane>>3, part=lane&7 owning 8 cols = 16 B).
// 8-wide unrolled gather. h[32][64] staged in XOR-swizzled LDS; waves 0/1
// run the 64x40 MFMA GEMM -> hw[N][64] bf16 (cols 0..39, 128-B rows).
// ---------------------------------------------------------------------------
__global__ __launch_bounds__(256) void agg1g2_k(const unsigned short* __restrict__ xw,
                                                const int* __restrict__ row_ptr,
                                                const int* __restrict__ csr,
                                                const float* __restrict__ b1,
                                                const unsigned short* __restrict__ w2s,
                                                const float* __restrict__ W2,
                                                unsigned short* __restrict__ hw, int N) {
  __shared__ uint4 hsm[32][8];            // 4 KB, XOR-swizzled on part
  int t = threadIdx.x;
  int wave = t >> 6, lane = t & 63;
  int blockRow0 = blockIdx.x * 32;
  int row = blockRow0 + wave * 8 + (lane >> 3);
  int part = lane & 7;
  bool live = row < N;

  int start = live ? row_ptr[row] : 0;
  int end   = live ? row_ptr[row + 1] : 0;

  float acc[8], bcc[8];
#pragma unroll
  for (int j = 0; j < 8; ++j) { acc[j] = 0.f; bcc[j] = 0.f; }

  int i = start;
  GATHER8(xw, 6)

  if (live) {
    int c0 = part << 3;
    float4 bA = *(const float4*)(b1 + c0);
    float4 bB = *(const float4*)(b1 + c0 + 4);
    float r0 = fmaxf(acc[0] + bcc[0] + bA.x, 0.f);
    float r1 = fmaxf(acc[1] + bcc[1] + bA.y, 0.f);
    float r2 = fmaxf(acc[2] + bcc[2] + bA.z, 0.f);
    float r3 = fmaxf(acc[3] + bcc[3] + bA.w, 0.f);
    float r4 = fmaxf(acc[4] + bcc[4] + bB.x, 0.f);
    float r5 = fmaxf(acc[5] + bcc[5] + bB.y, 0.f);
    float r6 = fmaxf(acc[6] + bcc[6] + bB.z, 0.f);
    float r7 = fmaxf(acc[7] + bcc[7] + bB.w, 0.f);
    uint4 o = make_uint4(packbf(r0, r1), packbf(r2, r3),
                         packbf(r4, r5), packbf(r6, r7));
    int lr = row - blockRow0;
    hsm[lr][part ^ (lr & 7)] = o;
  }
  __syncthreads();

  // ---- GEMM2: h[32][64] @ W2[64][40] -> hw (stride 64, cols 0..39) ----
  if (wave < 2) {
    int frow0 = blockRow0 + wave * 16;
    if (frow0 >= N) return;
    int m = lane & 15, q = lane >> 4;
    if (frow0 + 16 <= N) {
      short8 b[6];
#pragma unroll
      for (int f = 0; f < 6; ++f)
        b[f] = *(const short8*)(w2s + f * 512 + lane * 8);
      short8 a[2];
#pragma unroll
      for (int ks = 0; ks < 2; ++ks) {
        int lr = wave * 16 + m;
        int pp = ks * 4 + q;
        a[ks] = *(const short8*)&hsm[lr][pp ^ (lr & 7)];
      }
      f32x4 z = {0.f, 0.f, 0.f, 0.f};
      f32x4 acc2[3] = {z, z, z};
#pragma unroll
      for (int ct = 0; ct < 3; ++ct)
#pragma unroll
        for (int ks = 0; ks < 2; ++ks)
          acc2[ct] = __builtin_amdgcn_mfma_f32_16x16x32_bf16(
              a[ks], b[ct * 2 + ks], acc2[ct], 0, 0, 0);
#pragma unroll
      for (int ct = 0; ct < 3; ++ct)
#pragma unroll
        for (int r = 0; r < 4; ++r) {
          int row2 = frow0 + q * 4 + r;
          int c = ct * 16 + m;
          if (c < F_OUT) hw[(size_t)row2 * F_HID + c] = f2bf(acc2[ct][r]);
        }
    } else {
      for (int r = 0; r < 16; ++r) {            // tail rows (N%16 != 0)
        int row2 = frow0 + r;
        if (row2 >= N) break;
        if (lane < F_OUT) {
          int lr = wave * 16 + r;
          float s = 0.f;
          for (int k = 0; k < F_HID; ++k) {
            const unsigned short* hp =
                (const unsigned short*)&hsm[lr][(k >> 3) ^ (lr & 7)];
            s = fmaf(bf2f(hp[k & 7]), W2[k * F_OUT + lane], s);
          }
          hw[(size_t)row2 * F_HID + lane] = f2bf(s);
        }
      }
    }
  }
}

// ---------------------------------------------------------------------------
// Aggregation layer 2 + bias2 + log_softmax — 12 rows x 5 parts per wave,
// 8-wide unrolled gather. Softmax reduces across the 5-lane group via shfl.
// ---------------------------------------------------------------------------
__global__ __launch_bounds__(256) void agg2_ls_k(const unsigned short* __restrict__ hw,
                                                 const int* __restrict__ row_ptr,
                                                 const int* __restrict__ csr,
                                                 const float* __restrict__ b2,
                                                 float* __restrict__ out, int N) {
  int t = threadIdx.x;
  int wave = t >> 6, lane = t & 63;
  int grp = lane / 5;                      // 12 groups; lanes 60..63 idle
  int part = lane - grp * 5;
  int row = blockIdx.x * 48 + wave * 12 + grp;
  bool live = (grp < 12) && (row < N);

  int start = live ? row_ptr[row] : 0;
  int end   = live ? row_ptr[row + 1] : 0;

  float acc[8], bcc[8];
#pragma unroll
  for (int j = 0; j < 8; ++j) { acc[j] = 0.f; bcc[j] = 0.f; }

  int i = start;
  GATHER8(hw, 6)

  float vj[8];
  float mx = -3.4e38f;
  if (live) {
    int c0 = part << 3;
    float4 bA = *(const float4*)(b2 + c0);
    float4 bB = *(const float4*)(b2 + c0 + 4);
    vj[0] = acc[0] + bcc[0] + bA.x; vj[1] = acc[1] + bcc[1] + bA.y;
    vj[2] = acc[2] + bcc[2] + bA.z; vj[3] = acc[3] + bcc[3] + bA.w;
    vj[4] = acc[4] + bcc[4] + bB.x; vj[5] = acc[5] + bcc[5] + bB.y;
    vj[6] = acc[6] + bcc[6] + bB.z; vj[7] = acc[7] + bcc[7] + bB.w;
#pragma unroll
    for (int q = 0; q < 8; ++q) mx = fmaxf(mx, vj[q]);
  }
  int g0 = (grp < 12 ? grp : 0) * 5;
  float mxAll = mx;
#pragma unroll
  for (int q = 0; q < 5; ++q) mxAll = fmaxf(mxAll, __shfl(mx, g0 + q, 64));
  float ex = 0.f;
  if (live) {
#pragma unroll
    for (int q = 0; q < 8; ++q) ex += __expf(vj[q] - mxAll);
  }
  float exAll = 0.f;
#pragma unroll
  for (int q = 0; q < 5; ++q) exAll += __shfl(ex, g0 + q, 64);
  float lse = __logf(exAll) + mxAll;

  if (live) {
    int c0 = part << 3;
    float* op = out + (size_t)row * F_OUT + c0;
    *(float4*)op = make_float4(vj[0] - lse, vj[1] - lse, vj[2] - lse, vj[3] - lse);
    *(float4*)(op + 4) = make_float4(vj[4] - lse, vj[5] - lse, vj[6] - lse, vj[7] - lse);
  }
}

// ---------------------------------------------------------------------------
// ws layout (≈33 MB):
//   regA : xw[N,64] bf16
//   regB : ebuf[E] u32 — reused as hw[N,64] bf16 (ebuf dead after build)
//   row_ptr : N+1 | csr : E | counts : NBUCK*(NBLK+1) | w2s : 3072
// ---------------------------------------------------------------------------
extern "C" void kernel_launch(void* const* d_in, const int* in_sizes, int n_in,
                              void* d_out, int out_size, void* d_ws, size_t ws_size,
                              hipStream_t stream) {
  const float* x  = (const float*)d_in[0];
  const int*   ei = (const int*)d_in[1];
  const float* W1 = (const float*)d_in[2];
  const float* b1 = (const float*)d_in[3];
  const float* W2 = (const float*)d_in[4];
  const float* b2 = (const float*)d_in[5];

  int N = in_sizes[0] / F_IN;
  int E = in_sizes[1] / 2;

  char* base = (char*)d_ws;
  size_t szA = (size_t)N * F_HID * sizeof(unsigned short);
  size_t szEb = (size_t)E * sizeof(unsigned);
  size_t szHw = (size_t)N * F_HID * sizeof(unsigned short);
  size_t szB = (szEb > szHw) ? szEb : szHw;
  unsigned short* xw = (unsigned short*)base;
  char* regB = base + ((szA + 255) & ~(size_t)255);
  unsigned* ebuf       = (unsigned*)regB;
  unsigned short* hw   = (unsigned short*)regB;
  int* row_ptr = (int*)(regB + ((szB + 255) & ~(size_t)255));
  int* csr     = row_ptr + N + 1;
  int* counts  = csr + E;
  float* out = (float*)d_out;

  int NBLK  = (E + CHUNK - 1) / CHUNK;
  int NB1   = NBLK + 1;
  int NBUCK = (N + 511) >> BSH;
  unsigned short* w2s =
      (unsigned short*)(((uintptr_t)(counts + NBUCK * NB1) + 63) & ~(uintptr_t)63);
  int gemmGrid = (N + 63) / 64;
  int aggGrid1 = (N + 31) / 32;      // agg1g2: 32 rows per block
  int aggGrid2 = (N + 47) / 48;      // agg2: 48 rows per block (12/wave)

  // fused: pcount + w2s (blocks 0..NBLK-1) + gemm1 (remaining blocks)
  front_k<<<NBLK + gemmGrid, 256, 0, stream>>>(x, W1, W2, w2s, xw, N,
                                               ei, counts, E, NBLK, NB1, NBUCK);

  scanR_k<<<NBUCK, 256, 0, stream>>>(counts, NBLK, NB1);
  partition_k<<<NBLK, 256, 0, stream>>>(counts, ei, ebuf, E, NBLK, NB1, NBUCK);
  build_k<<<NBUCK, BLD_T, 0, stream>>>(ebuf, counts, row_ptr, csr,
                                       N, E, NBLK, NB1, NBUCK);

  agg1g2_k<<<aggGrid1, 256, 0, stream>>>(xw, row_ptr, csr, b1, w2s, W2, hw, N);
  agg2_ls_k<<<aggGrid2, 256, 0, stream>>>(hw, row_ptr, csr, b2, out, N);
}